// Round 13
// baseline (78.886 us; speedup 1.0000x reference)
//
#include <hip/hip_runtime.h>
#include <hip/hip_bf16.h>

// HardAttention = GEMM out=tanh([ctx|outp]@W^T+b) (M=16384,K=1024,N=512, bf16 MFMA)
//               + attn = constant one-hot [4,4096,4096] (256 MiB write stream).
// R12 post-mortem: stores(t) were issued BEFORE loads(t+2), so every WAITV for loads also
// forced 2-iteration-old NT stores to drain -> GEMM chained to the fill's store-drain rate.
// R13 = R12 with ISSUE moved BEFORE stores (stores always newest in the vmem queue; no wait
// ever forces them) + exact per-t wait constants: t0=16, t1=20, steady=24, t31=8.

typedef __attribute__((ext_vector_type(8))) short bf16x8;   // 8 bf16 = 4 VGPRs
typedef __attribute__((ext_vector_type(4))) float f32x4;

#define B_N 4
#define L_N 4096
#define S_N 4096
#define D_N 512
#define M_N (B_N * L_N)   // 16384
#define K_N (2 * D_N)     // 1024

#define NTHREADS 256      // 4 waves/block
#define NBLOCKS 512       // 2048 waves = 256 mtiles(64) x 8 ntiles(64)
#define NSTEPS 32         // K / 32

static __device__ __forceinline__ short f2bf(float f) {
  return __builtin_bit_cast(short, __float2bfloat16(f));   // RNE; fuses to v_cvt_pk_bf16_f32
}

static __device__ __forceinline__ bf16x8 pack8(f32x4 a, f32x4 b) {
  bf16x8 r;
  r[0] = f2bf(a.x); r[1] = f2bf(a.y); r[2] = f2bf(a.z); r[3] = f2bf(a.w);
  r[4] = f2bf(b.x); r[5] = f2bf(b.y); r[6] = f2bf(b.z); r[7] = f2bf(b.w);
  return r;
}

static __device__ __forceinline__ void gload16(const float* g, char* l) {
  __builtin_amdgcn_global_load_lds(
      (const __attribute__((address_space(1))) unsigned*)g,
      (__attribute__((address_space(3))) unsigned*)l, 16, 0, 0);
}

#define WAITV(N)                                                    \
  asm volatile("s_waitcnt vmcnt(" #N ")" ::: "memory");             \
  __builtin_amdgcn_sched_barrier(0)
#define WAITL0                                                      \
  asm volatile("s_waitcnt lgkmcnt(0)" ::: "memory");                \
  __builtin_amdgcn_sched_barrier(0)

__global__ __launch_bounds__(NTHREADS, 1)
void gemm_fill(const float* __restrict__ outp, const float* __restrict__ ctx,
               const float* __restrict__ Wm, const float* __restrict__ bias,
               float* __restrict__ dout)
{
  // per-wave 32KB: ring{2} x { A-tile 8KB (64r x 128B f32) , W-tile 8KB }
  __shared__ char lds[4 * 32768];   // 128 KiB -> 1 block/CU

  const int tid  = threadIdx.x;
  const int lane = tid & 63;
  const int wid  = tid >> 6;
  const int gwave = blockIdx.x * 4 + wid;
  const int mtile = gwave >> 3;       // 256 tiles of 64 rows
  const int ntile = gwave & 7;        // 8 tiles of 64 cols
  const int m0 = mtile * 64;
  const int n0 = ntile * 64;

  char* ldsBase = &lds[wid * 32768];

  // ---- staging source map (pre-swizzled, rule 21): instr i covers rows i*8..i*8+7.
  // lane l -> row r = i*8 + (l>>3), LDS slot s = l&7; source slot s' = s ^ (r&7).
  const int sprime   = (lane & 7) ^ (lane >> 3);
  const int aLaneOff = (m0 + (lane >> 3)) * D_N + sprime * 4;   // float units
  const int wLaneOff = (n0 + (lane >> 3)) * K_N + sprime * 4;

  // ---- read map: frag row R = i*16 + l15; global slot g read at LDS slot g^(R&7);
  // R&7 == l15&7 since i*16 % 8 == 0.
  const int l15 = lane & 15;
  const int lq  = lane >> 4;          // k-slice: f32 k = lq*8 .. +7 (slots 2lq, 2lq+1)
  const int x15 = l15 & 7;
  const int rd0 = l15 * 128 + (((lq * 2)     ^ x15) << 4);
  const int rd1 = l15 * 128 + (((lq * 2 + 1) ^ x15) << 4);

  // fill: this wave covers f32x4 indices [gwave*8192, (gwave+1)*8192)
  f32x4* attn4 = (f32x4*)(dout + (size_t)M_N * D_N) + (size_t)gwave * 8192;

  f32x4 acc[4][4] = {};

#define ISSUE(TT)                                                               \
  {                                                                             \
    const int tt_ = (TT);                                                       \
    const float* as_ = (tt_ < 16 ? ctx : outp) + aLaneOff + (tt_ & 15) * 32;    \
    const float* ws_ = Wm + wLaneOff + tt_ * 32;                                \
    char* db_ = ldsBase + (tt_ & 1) * 16384;                                    \
    _Pragma("unroll")                                                           \
    for (int i = 0; i < 8; ++i) {                                               \
      gload16(as_ + i * (8 * D_N), db_ + i * 1024);                             \
      gload16(ws_ + i * (8 * K_N), db_ + 8192 + i * 1024);                      \
    }                                                                           \
  }

  // ---- prologue: batches 0,1 in flight ----
  ISSUE(0)
  ISSUE(1)

#pragma unroll 1
  for (int t = 0; t < NSTEPS; ++t) {
    // ledger (queue oldest->newest at top of iter t, steady state):
    //   [L(t)16, S(t-2)4, L(t+1)16, S(t-1)4] = 40 outstanding.
    // Force L(t) only -> allow newest 24. Stores are never forced in steady state.
    if (t == 0)       { WAITV(16); }   // [L0,L1]=32 -> force L0
    else if (t == 1)  { WAITV(20); }   // [L1,L2,S0]=36 -> force L1 only
    else if (t == 31) { WAITV(8);  }   // [L31,S29,S30]=24 -> force L31 only
    else              { WAITV(24); }

    // ---- swizzled ds_read (f32) + cvt -> fragments ----
    const char* rb = ldsBase + (t & 1) * 16384;
    bf16x8 af[4], wf[4];
#pragma unroll
    for (int i = 0; i < 4; ++i) {
      f32x4 lo = *(const f32x4*)(rb + i * 2048 + rd0);
      f32x4 hi = *(const f32x4*)(rb + i * 2048 + rd1);
      af[i] = pack8(lo, hi);
    }
#pragma unroll
    for (int j = 0; j < 4; ++j) {
      f32x4 lo = *(const f32x4*)(rb + 8192 + j * 2048 + rd0);
      f32x4 hi = *(const f32x4*)(rb + 8192 + j * 2048 + rd1);
      wf[j] = pack8(lo, hi);
    }
    WAITL0;   // ds_reads retired -> buf[t&1] reusable by batch t+2

    // ---- batch t+2 loads FIRST (so no future wait ever forces the stores) ----
    if (t + 2 < NSTEPS) ISSUE(t + 2)

    // ---- fill stores (always newest in the vmem queue) ----
#pragma unroll
    for (int s = 0; s < 4; ++s) {
      const int li = t * 256 + (s << 6) + lane;        // local f32x4 idx
      const int gi = (gwave << 13) + li;
      const int col4 = (gi & 1023) << 2;
      const int l    = (gi >> 10) & 4095;
      f32x4 v;
      v.x = (col4     == l) ? 1.0f : 0.0f;
      v.y = (col4 + 1 == l) ? 1.0f : 0.0f;
      v.z = (col4 + 2 == l) ? 1.0f : 0.0f;
      v.w = (col4 + 3 == l) ? 1.0f : 0.0f;
      __builtin_nontemporal_store(v, attn4 + li);
    }

    // ---- 16 MFMA ----
#pragma unroll
    for (int i = 0; i < 4; ++i)
#pragma unroll
      for (int j = 0; j < 4; ++j)
        acc[i][j] = __builtin_amdgcn_mfma_f32_16x16x32_bf16(af[i], wf[j], acc[i][j], 0, 0, 0);
  }
#undef ISSUE

  // ---- epilogue: C/D layout col=lane&15, row=(lane>>4)*4+reg (verified R1/m89/m91) ----
  const int r0  = m0 + (lq << 2);
  const int c0g = n0 + l15;
  float bv[4];
#pragma unroll
  for (int j = 0; j < 4; ++j) bv[j] = bias[c0g + j * 16];
#pragma unroll
  for (int i = 0; i < 4; ++i)
#pragma unroll
    for (int j = 0; j < 4; ++j)
#pragma unroll
      for (int r = 0; r < 4; ++r) {
        const int m = r0 + i * 16 + r;
        const int n = c0g + j * 16;
        dout[(size_t)m * D_N + n] = tanhf(acc[i][j][r] + bv[j]);
      }
}

extern "C" void kernel_launch(void* const* d_in, const int* in_sizes, int n_in,
                              void* d_out, int out_size, void* d_ws, size_t ws_size,
                              hipStream_t stream) {
  const float* outp = (const float*)d_in[0];
  const float* ctx  = (const float*)d_in[1];
  const float* Wm   = (const float*)d_in[2];
  const float* bias = (const float*)d_in[3];
  float* dout = (float*)d_out;
  hipLaunchKernelGGL(gemm_fill, dim3(NBLOCKS), dim3(NTHREADS), 0, stream,
                     outp, ctx, Wm, bias, dout);
}

// Round 14
// 68.403 us; speedup vs baseline: 1.1532x; 1.1532x over previous
//
#include <hip/hip_runtime.h>
#include <hip/hip_bf16.h>

// HardAttention = GEMM out=tanh([ctx|outp]@W^T+b) (M=16384,K=1024,N=512, bf16 MFMA)
//               + attn = constant one-hot [4,4096,4096] (256 MiB write stream).
// R13 post-mortem: wave-autonomous 64x64 tiles re-stage A x8 / W x256 = ~1GB cache-side
// loads at the ~14 TB/s staging ceiling = the 74us wall. R14: blocked 128x128 tile
// (4 waves) cuts staged bytes to ~320MB; the __syncthreads vmcnt(0) trap (R1/R6) is
// avoided via the m201-style protocol: global_load_lds f32 staging, ring-2, per-wave
// counted WAITV + raw s_barrier x2 per step (read-ready / reuse-safe), fill stores
// issued newest so no wait ever forces them. cvt f32->bf16 after ds_read.
// Ledger (per wave, top of iter t): steady [L(t)8,S(t-2)4,L(t+1)8,S(t-1)4] -> WAITV(16);
// t0->8 (prologue 16 out), t1->12 ([L1,L2,S0]=20), t31->8 ([L31,S29,S30]=16).

typedef __attribute__((ext_vector_type(8))) short bf16x8;   // 8 bf16 = 4 VGPRs
typedef __attribute__((ext_vector_type(4))) float f32x4;

#define B_N 4
#define L_N 4096
#define S_N 4096
#define D_N 512
#define M_N (B_N * L_N)   // 16384
#define K_N (2 * D_N)     // 1024

#define NTHREADS 256      // 4 waves/block; each wave owns a 64x64 C sub-tile
#define NBLOCKS 512       // (16384/128) x (512/128) = 128 x 4
#define NSTEPS 32         // K / 32

static __device__ __forceinline__ short f2bf(float f) {
  return __builtin_bit_cast(short, __float2bfloat16(f));   // RNE
}

static __device__ __forceinline__ bf16x8 pack8(f32x4 a, f32x4 b) {
  bf16x8 r;
  r[0] = f2bf(a.x); r[1] = f2bf(a.y); r[2] = f2bf(a.z); r[3] = f2bf(a.w);
  r[4] = f2bf(b.x); r[5] = f2bf(b.y); r[6] = f2bf(b.z); r[7] = f2bf(b.w);
  return r;
}

static __device__ __forceinline__ void gload16(const float* g, char* l) {
  __builtin_amdgcn_global_load_lds(
      (const __attribute__((address_space(1))) unsigned*)g,
      (__attribute__((address_space(3))) unsigned*)l, 16, 0, 0);
}

#define WAITV(N)                                                    \
  asm volatile("s_waitcnt vmcnt(" #N ")" ::: "memory");             \
  __builtin_amdgcn_sched_barrier(0)
#define WAITL0                                                      \
  asm volatile("s_waitcnt lgkmcnt(0)" ::: "memory");                \
  __builtin_amdgcn_sched_barrier(0)
#define BAR()                                                       \
  __builtin_amdgcn_s_barrier();                                     \
  __builtin_amdgcn_sched_barrier(0)

__global__ __launch_bounds__(NTHREADS, 2)
void gemm_fill(const float* __restrict__ outp, const float* __restrict__ ctx,
               const float* __restrict__ Wm, const float* __restrict__ bias,
               float* __restrict__ dout)
{
  // ring{2} x { A-tile 16KB (128r x 128B f32) } and same for W: 64 KB total -> 2 blocks/CU
  __shared__ char ldsA[32768];
  __shared__ char ldsW[32768];

  const int tid  = threadIdx.x;
  const int lane = tid & 63;
  const int wid  = tid >> 6;

  // XCD-chunked bijective swizzle (512 = 8*64): the 4 blocks sharing an A panel
  // (consecutive logical ids) stay on one XCD's L2.
  const int sb = (blockIdx.x & 7) * 64 + (blockIdx.x >> 3);
  const int mt = sb >> 2;           // 128 m-tiles of 128 rows
  const int nt = sb & 3;            // 4 n-tiles of 128 cols
  const int m0 = mt * 128;
  const int n0 = nt * 128;

  const int wr = (wid >> 1) * 64;   // wave sub-tile inside 128x128
  const int wc = (wid & 1) * 64;

  // staging source map (pre-swizzled, rule 21): per instr i (0..3) this wave covers
  // rows wid*32+i*8..+7. lane l -> row +(l>>3), LDS slot l&7, source slot (l&7)^((l>>3)&7).
  const int srcSlot  = (lane & 7) ^ ((lane >> 3) & 7);
  const int aRowBase = (m0 + wid * 32 + (lane >> 3)) * D_N + srcSlot * 4;
  const int wRowBase = (n0 + wid * 32 + (lane >> 3)) * K_N + srcSlot * 4;
  const int stgOff   = wid * 32 * 128;   // this wave's 32-row slab (bytes)

  // frag read map: row R slot g read at LDS slot g^(R&7); R&7 == l15&7 (tiles are 16-aligned)
  const int l15 = lane & 15;
  const int lq  = lane >> 4;          // k-slice: f32 k = lq*8..+7 = slots 2lq,2lq+1
  const int x15 = l15 & 7;
  const int rd0 = ((2 * lq)     ^ x15) << 4;
  const int rd1 = ((2 * lq + 1) ^ x15) << 4;

  // fill: this block covers f32x4 indices [sb*32768, (sb+1)*32768)
  f32x4* attn4 = (f32x4*)(dout + (size_t)M_N * D_N) + (size_t)sb * 32768;

  f32x4 acc[4][4] = {};

#define ISSUE(TT)                                                               \
  {                                                                             \
    const int tt_ = (TT);                                                       \
    const float* as_ = (tt_ < 16 ? ctx : outp) + aRowBase + (tt_ & 15) * 32;    \
    const float* ws_ = Wm + wRowBase + tt_ * 32;                                \
    char* da_ = ldsA + (tt_ & 1) * 16384 + stgOff;                              \
    char* dw_ = ldsW + (tt_ & 1) * 16384 + stgOff;                              \
    _Pragma("unroll")                                                           \
    for (int i = 0; i < 4; ++i) {                                               \
      gload16(as_ + i * (8 * D_N), da_ + i * 1024);                             \
      gload16(ws_ + i * (8 * K_N), dw_ + i * 1024);                             \
    }                                                                           \
  }

  // ---- prologue: batches 0,1 in flight (16 outstanding per wave) ----
  ISSUE(0)
  ISSUE(1)

#pragma unroll 1
  for (int t = 0; t < NSTEPS; ++t) {
    if (t == 0)              { WAITV(8);  }
    else if (t == 1)         { WAITV(12); }
    else if (t == NSTEPS - 1){ WAITV(8);  }
    else                     { WAITV(16); }
    BAR();   // all waves' L(t) complete -> tile t readable

    // ---- swizzled ds_read of my fragments (f32) ----
    const char* rbA = ldsA + (t & 1) * 16384;
    const char* rbW = ldsW + (t & 1) * 16384;
    f32x4 alo[4], ahi[4], wlo[4], whi[4];
#pragma unroll
    for (int i = 0; i < 4; ++i) {
      const int Ra = (wr + i * 16 + l15) * 128;
      alo[i] = *(const f32x4*)(rbA + Ra + rd0);
      ahi[i] = *(const f32x4*)(rbA + Ra + rd1);
      const int Rw = (wc + i * 16 + l15) * 128;
      wlo[i] = *(const f32x4*)(rbW + Rw + rd0);
      whi[i] = *(const f32x4*)(rbW + Rw + rd1);
    }
    WAITL0;  // my reads retired (values in regs)
    BAR();   // ALL waves' reads retired -> buf[t&1] safe to overwrite

    // ---- batch t+2 (overwrites buf[t&1]) then fill stores (newest in queue) ----
    if (t + 2 < NSTEPS) ISSUE(t + 2)

#pragma unroll
    for (int s = 0; s < 4; ++s) {
      const int li = t * 1024 + s * 256 + tid;     // block-local f32x4 idx
      const int gi = sb * 32768 + li;
      const int col4 = (gi & 1023) << 2;
      const int l_   = (gi >> 10) & 4095;
      f32x4 v;
      v.x = (col4     == l_) ? 1.0f : 0.0f;
      v.y = (col4 + 1 == l_) ? 1.0f : 0.0f;
      v.z = (col4 + 2 == l_) ? 1.0f : 0.0f;
      v.w = (col4 + 3 == l_) ? 1.0f : 0.0f;
      __builtin_nontemporal_store(v, attn4 + li);
    }

    // ---- cvt + 16 MFMA ----
    bf16x8 af[4], wf[4];
#pragma unroll
    for (int i = 0; i < 4; ++i) {
      af[i] = pack8(alo[i], ahi[i]);
      wf[i] = pack8(wlo[i], whi[i]);
    }
#pragma unroll
    for (int i = 0; i < 4; ++i)
#pragma unroll
      for (int j = 0; j < 4; ++j)
        acc[i][j] = __builtin_amdgcn_mfma_f32_16x16x32_bf16(af[i], wf[j], acc[i][j], 0, 0, 0);
  }
#undef ISSUE

  // ---- epilogue: C/D layout col=lane&15, row=(lane>>4)*4+reg (verified R1/m89/m91) ----
  const int r0  = m0 + wr + (lq << 2);
  const int c0g = n0 + wc + l15;
  float bv[4];
#pragma unroll
  for (int j = 0; j < 4; ++j) bv[j] = bias[c0g + j * 16];
#pragma unroll
  for (int i = 0; i < 4; ++i)
#pragma unroll
    for (int j = 0; j < 4; ++j)
#pragma unroll
      for (int r = 0; r < 4; ++r) {
        const int m = r0 + i * 16 + r;
        const int n = c0g + j * 16;
        dout[(size_t)m * D_N + n] = tanhf(acc[i][j][r] + bv[j]);
      }
}

extern "C" void kernel_launch(void* const* d_in, const int* in_sizes, int n_in,
                              void* d_out, int out_size, void* d_ws, size_t ws_size,
                              hipStream_t stream) {
  const float* outp = (const float*)d_in[0];
  const float* ctx  = (const float*)d_in[1];
  const float* Wm   = (const float*)d_in[2];
  const float* bias = (const float*)d_in[3];
  float* dout = (float*)d_out;
  hipLaunchKernelGGL(gemm_fill, dim3(NBLOCKS), dim3(NTHREADS), 0, stream,
                     outp, ctx, Wm, bias, dout);
}

// Round 15
// 66.657 us; speedup vs baseline: 1.1835x; 1.0262x over previous
//
#include <hip/hip_runtime.h>
#include <hip/hip_bf16.h>

// HardAttention = GEMM out=tanh([ctx|outp]@W^T+b) (M=16384,K=1024,N=512, bf16 MFMA)
//               + attn = constant one-hot [4,4096,4096] (256 MiB write stream).
// R14 (68.4us): blocked 128x128, counted-vmcnt + raw-barrier ring-2 pipeline. The kernel is
// now additive-memory-bound: HBM 371MB mandatory + 524MB cache-side staging (A x4, W x128).
// R15: BM=256 x BN=128 halves W staging redundancy (x128 -> x64, saves 128MB fabric).
// 256 blocks = exactly 1/CU (one residency round), 8 waves/block = 2 waves/SIMD (TLP
// unchanged). LDS 96KB: A-ring2 64KB + W-ring2 32KB. Same protocol/swizzle/ledger form.
// Ledger/wave (L=6/step): steady [L(t)6,S(t-2)4,L(t+1)6,S(t-1)4] -> WAITV(14);
// t0 -> 6, t1 -> 10 ([L1,S0,L2]=16), t31 -> 8 ([L31,S29,S30]=14).

typedef __attribute__((ext_vector_type(8))) short bf16x8;   // 8 bf16 = 4 VGPRs
typedef __attribute__((ext_vector_type(4))) float f32x4;

#define B_N 4
#define L_N 4096
#define S_N 4096
#define D_N 512
#define M_N (B_N * L_N)   // 16384
#define K_N (2 * D_N)     // 1024

#define NTHREADS 512      // 8 waves/block; each wave owns a 64x64 C sub-tile
#define NBLOCKS 256       // (16384/256) x (512/128) = 64 x 4 -> exactly 1 block/CU
#define NSTEPS 32         // K / 32

static __device__ __forceinline__ short f2bf(float f) {
  return __builtin_bit_cast(short, __float2bfloat16(f));   // RNE
}

static __device__ __forceinline__ bf16x8 pack8(f32x4 a, f32x4 b) {
  bf16x8 r;
  r[0] = f2bf(a.x); r[1] = f2bf(a.y); r[2] = f2bf(a.z); r[3] = f2bf(a.w);
  r[4] = f2bf(b.x); r[5] = f2bf(b.y); r[6] = f2bf(b.z); r[7] = f2bf(b.w);
  return r;
}

static __device__ __forceinline__ void gload16(const float* g, char* l) {
  __builtin_amdgcn_global_load_lds(
      (const __attribute__((address_space(1))) unsigned*)g,
      (__attribute__((address_space(3))) unsigned*)l, 16, 0, 0);
}

#define WAITV(N)                                                    \
  asm volatile("s_waitcnt vmcnt(" #N ")" ::: "memory");             \
  __builtin_amdgcn_sched_barrier(0)
#define WAITL0                                                      \
  asm volatile("s_waitcnt lgkmcnt(0)" ::: "memory");                \
  __builtin_amdgcn_sched_barrier(0)
#define BAR()                                                       \
  __builtin_amdgcn_s_barrier();                                     \
  __builtin_amdgcn_sched_barrier(0)

__global__ __launch_bounds__(NTHREADS, 1)
void gemm_fill(const float* __restrict__ outp, const float* __restrict__ ctx,
               const float* __restrict__ Wm, const float* __restrict__ bias,
               float* __restrict__ dout)
{
  // ring{2} x { A-tile 32KB (256r x 128B f32) } + ring{2} x { W-tile 16KB (128r x 128B) }
  __shared__ char ldsA[65536];
  __shared__ char ldsW[32768];

  const int tid  = threadIdx.x;
  const int lane = tid & 63;
  const int wid  = tid >> 6;         // 0..7

  // XCD-chunked bijective swizzle (256 = 8*32): consecutive logical ids (sharing an
  // A panel, 4 per m-tile) stay on one XCD's L2.
  const int sb = (blockIdx.x & 7) * 32 + (blockIdx.x >> 3);
  const int mt = sb >> 2;           // 64 m-tiles of 256 rows
  const int nt = sb & 3;            // 4 n-tiles of 128 cols
  const int m0 = mt * 256;
  const int n0 = nt * 128;

  const int wr = (wid >> 1) * 64;   // wave sub-tile inside 256x128
  const int wc = (wid & 1) * 64;

  // staging source map (pre-swizzled, rule 21): A instr i (0..3) covers rows
  // wid*32+i*8..+7; W instr i (0..1) covers rows wid*16+i*8..+7.
  // lane l -> row +(l>>3), LDS slot l&7, source slot (l&7)^((l>>3)&7).
  const int srcSlot  = (lane & 7) ^ ((lane >> 3) & 7);
  const int aRowBase = (m0 + wid * 32 + (lane >> 3)) * D_N + srcSlot * 4;
  const int wRowBase = (n0 + wid * 16 + (lane >> 3)) * K_N + srcSlot * 4;
  const int stgOffA  = wid * 32 * 128;   // this wave's 32-row A slab (bytes)
  const int stgOffW  = wid * 16 * 128;   // this wave's 16-row W slab (bytes)

  // frag read map: row R slot g read at LDS slot g^(R&7); R&7 == l15&7 (16-aligned tiles)
  const int l15 = lane & 15;
  const int lq  = lane >> 4;          // k-slice: f32 k = lq*8..+7 = slots 2lq,2lq+1
  const int x15 = l15 & 7;
  const int rd0 = ((2 * lq)     ^ x15) << 4;
  const int rd1 = ((2 * lq + 1) ^ x15) << 4;

  // fill: this block covers f32x4 indices [sb*65536, (sb+1)*65536)
  f32x4* attn4 = (f32x4*)(dout + (size_t)M_N * D_N) + (size_t)sb * 65536;

  f32x4 acc[4][4] = {};

#define ISSUE(TT)                                                               \
  {                                                                             \
    const int tt_ = (TT);                                                       \
    const float* as_ = (tt_ < 16 ? ctx : outp) + aRowBase + (tt_ & 15) * 32;    \
    const float* ws_ = Wm + wRowBase + tt_ * 32;                                \
    char* da_ = ldsA + (tt_ & 1) * 32768 + stgOffA;                             \
    char* dw_ = ldsW + (tt_ & 1) * 16384 + stgOffW;                             \
    _Pragma("unroll")                                                           \
    for (int i = 0; i < 4; ++i)                                                 \
      gload16(as_ + i * (8 * D_N), da_ + i * 1024);                             \
    _Pragma("unroll")                                                           \
    for (int i = 0; i < 2; ++i)                                                 \
      gload16(ws_ + i * (8 * K_N), dw_ + i * 1024);                             \
  }

  // ---- prologue: batches 0,1 in flight (12 outstanding per wave) ----
  ISSUE(0)
  ISSUE(1)

#pragma unroll 1
  for (int t = 0; t < NSTEPS; ++t) {
    if (t == 0)               { WAITV(6);  }
    else if (t == 1)          { WAITV(10); }
    else if (t == NSTEPS - 1) { WAITV(8);  }
    else                      { WAITV(14); }
    BAR();   // all waves' L(t) complete -> tile t readable

    // ---- swizzled ds_read of my fragments (f32) ----
    const char* rbA = ldsA + (t & 1) * 32768;
    const char* rbW = ldsW + (t & 1) * 16384;
    f32x4 alo[4], ahi[4], wlo[4], whi[4];
#pragma unroll
    for (int i = 0; i < 4; ++i) {
      const int Ra = (wr + i * 16 + l15) * 128;
      alo[i] = *(const f32x4*)(rbA + Ra + rd0);
      ahi[i] = *(const f32x4*)(rbA + Ra + rd1);
      const int Rw = (wc + i * 16 + l15) * 128;
      wlo[i] = *(const f32x4*)(rbW + Rw + rd0);
      whi[i] = *(const f32x4*)(rbW + Rw + rd1);
    }
    WAITL0;  // my reads retired (values in regs)
    BAR();   // ALL waves' reads retired -> buf[t&1] safe to overwrite

    // ---- batch t+2 (overwrites buf[t&1]) then fill stores (newest in queue) ----
    if (t + 2 < NSTEPS) ISSUE(t + 2)

#pragma unroll
    for (int s = 0; s < 4; ++s) {
      const int li = t * 2048 + s * 512 + tid;     // block-local f32x4 idx
      const int gi = sb * 65536 + li;
      const int col4 = (gi & 1023) << 2;
      const int l_   = (gi >> 10) & 4095;
      f32x4 v;
      v.x = (col4     == l_) ? 1.0f : 0.0f;
      v.y = (col4 + 1 == l_) ? 1.0f : 0.0f;
      v.z = (col4 + 2 == l_) ? 1.0f : 0.0f;
      v.w = (col4 + 3 == l_) ? 1.0f : 0.0f;
      __builtin_nontemporal_store(v, attn4 + li);
    }

    // ---- cvt + 16 MFMA ----
    bf16x8 af[4], wf[4];
#pragma unroll
    for (int i = 0; i < 4; ++i) {
      af[i] = pack8(alo[i], ahi[i]);
      wf[i] = pack8(wlo[i], whi[i]);
    }
#pragma unroll
    for (int i = 0; i < 4; ++i)
#pragma unroll
      for (int j = 0; j < 4; ++j)
        acc[i][j] = __builtin_amdgcn_mfma_f32_16x16x32_bf16(af[i], wf[j], acc[i][j], 0, 0, 0);
  }
#undef ISSUE

  // ---- epilogue: C/D layout col=lane&15, row=(lane>>4)*4+reg (verified R1/m89/m91) ----
  const int r0  = m0 + wr + (lq << 2);
  const int c0g = n0 + wc + l15;
  float bv[4];
#pragma unroll
  for (int j = 0; j < 4; ++j) bv[j] = bias[c0g + j * 16];
#pragma unroll
  for (int i = 0; i < 4; ++i)
#pragma unroll
    for (int j = 0; j < 4; ++j)
#pragma unroll
      for (int r = 0; r < 4; ++r) {
        const int m = r0 + i * 16 + r;
        const int n = c0g + j * 16;
        dout[(size_t)m * D_N + n] = tanhf(acc[i][j][r] + bv[j]);
      }
}

extern "C" void kernel_launch(void* const* d_in, const int* in_sizes, int n_in,
                              void* d_out, int out_size, void* d_ws, size_t ws_size,
                              hipStream_t stream) {
  const float* outp = (const float*)d_in[0];
  const float* ctx  = (const float*)d_in[1];
  const float* Wm   = (const float*)d_in[2];
  const float* bias = (const float*)d_in[3];
  float* dout = (float*)d_out;
  hipLaunchKernelGGL(gemm_fill, dim3(NBLOCKS), dim3(NTHREADS), 0, stream,
                     outp, ctx, Wm, bias, dout);
}

// Round 16
// 57.320 us; speedup vs baseline: 1.3762x; 1.1629x over previous
//
#include <hip/hip_runtime.h>
#include <hip/hip_bf16.h>

// HardAttention = GEMM out=tanh([ctx|outp]@W^T+b) (M=16384,K=1024,N=512, bf16 MFMA)
//               + attn = constant one-hot [4,4096,4096] (256 MiB write stream).
// R15 (66.7us): BM256xBN128 blocked, ring-2, counted vmcnt, 2 barriers + lgkmcnt(0)/step.
// R16: RING-3, ONE barrier/step, no explicit lgkm wait. ISSUE(t+2) now targets
// buf[(t+2)%3] != buf[t%3]; safety: BAR(t) rendezvous implies every wave consumed its
// step t-1 ds_reads (MFMA data-deps -> compiler-counted lgkm), so the last reader of
// buf[(t+2)%3]=buf[(t-1)%3] is done before any wave's ISSUE(t+2). Waves may drift within
// a step -> issue/compute role overlap. Ledger unchanged: t0=6, t1=10, steady=14, t31=8.
// LDS 144KB (A ring3 96KB + W ring3 48KB), 1 block/CU, 256 blocks = 1 residency round.

typedef __attribute__((ext_vector_type(8))) short bf16x8;   // 8 bf16 = 4 VGPRs
typedef __attribute__((ext_vector_type(4))) float f32x4;

#define B_N 4
#define L_N 4096
#define S_N 4096
#define D_N 512
#define M_N (B_N * L_N)   // 16384
#define K_N (2 * D_N)     // 1024

#define NTHREADS 512      // 8 waves/block; each wave owns a 64x64 C sub-tile
#define NBLOCKS 256       // (16384/256) x (512/128) = 64 x 4 -> exactly 1 block/CU
#define NSTEPS 32         // K / 32

static __device__ __forceinline__ short f2bf(float f) {
  return __builtin_bit_cast(short, __float2bfloat16(f));   // RNE
}

static __device__ __forceinline__ bf16x8 pack8(f32x4 a, f32x4 b) {
  bf16x8 r;
  r[0] = f2bf(a.x); r[1] = f2bf(a.y); r[2] = f2bf(a.z); r[3] = f2bf(a.w);
  r[4] = f2bf(b.x); r[5] = f2bf(b.y); r[6] = f2bf(b.z); r[7] = f2bf(b.w);
  return r;
}

static __device__ __forceinline__ void gload16(const float* g, char* l) {
  __builtin_amdgcn_global_load_lds(
      (const __attribute__((address_space(1))) unsigned*)g,
      (__attribute__((address_space(3))) unsigned*)l, 16, 0, 0);
}

#define WAITV(N)                                                    \
  asm volatile("s_waitcnt vmcnt(" #N ")" ::: "memory");             \
  __builtin_amdgcn_sched_barrier(0)
#define BAR()                                                       \
  __builtin_amdgcn_s_barrier();                                     \
  __builtin_amdgcn_sched_barrier(0)

__global__ __launch_bounds__(NTHREADS, 1)
void gemm_fill(const float* __restrict__ outp, const float* __restrict__ ctx,
               const float* __restrict__ Wm, const float* __restrict__ bias,
               float* __restrict__ dout)
{
  // ring{3} x { A-tile 32KB (256r x 128B f32) } + ring{3} x { W-tile 16KB (128r x 128B) }
  __shared__ char ldsA[3 * 32768];   // 96 KB
  __shared__ char ldsW[3 * 16384];   // 48 KB

  const int tid  = threadIdx.x;
  const int lane = tid & 63;
  const int wid  = tid >> 6;         // 0..7

  // XCD-chunked bijective swizzle (256 = 8*32): consecutive logical ids (sharing an
  // A panel, 4 per m-tile) stay on one XCD's L2.
  const int sb = (blockIdx.x & 7) * 32 + (blockIdx.x >> 3);
  const int mt = sb >> 2;           // 64 m-tiles of 256 rows
  const int nt = sb & 3;            // 4 n-tiles of 128 cols
  const int m0 = mt * 256;
  const int n0 = nt * 128;

  const int wr = (wid >> 1) * 64;   // wave sub-tile inside 256x128
  const int wc = (wid & 1) * 64;

  // staging source map (pre-swizzled, rule 21): A instr i (0..3) covers rows
  // wid*32+i*8..+7; W instr i (0..1) covers rows wid*16+i*8..+7.
  // lane l -> row +(l>>3), LDS slot l&7, source slot (l&7)^((l>>3)&7).
  const int srcSlot  = (lane & 7) ^ ((lane >> 3) & 7);
  const int aRowBase = (m0 + wid * 32 + (lane >> 3)) * D_N + srcSlot * 4;
  const int wRowBase = (n0 + wid * 16 + (lane >> 3)) * K_N + srcSlot * 4;
  const int stgOffA  = wid * 32 * 128;   // this wave's 32-row A slab (bytes)
  const int stgOffW  = wid * 16 * 128;   // this wave's 16-row W slab (bytes)

  // frag read map: row R slot g read at LDS slot g^(R&7); R&7 == l15&7 (16-aligned tiles)
  const int l15 = lane & 15;
  const int lq  = lane >> 4;          // k-slice: f32 k = lq*8..+7 = slots 2lq,2lq+1
  const int x15 = l15 & 7;
  const int rd0 = ((2 * lq)     ^ x15) << 4;
  const int rd1 = ((2 * lq + 1) ^ x15) << 4;

  // fill: this block covers f32x4 indices [sb*65536, (sb+1)*65536)
  f32x4* attn4 = (f32x4*)(dout + (size_t)M_N * D_N) + (size_t)sb * 65536;

  f32x4 acc[4][4] = {};

#define ISSUE(TT, BI)                                                           \
  {                                                                             \
    const int tt_ = (TT);                                                       \
    const float* as_ = (tt_ < 16 ? ctx : outp) + aRowBase + (tt_ & 15) * 32;    \
    const float* ws_ = Wm + wRowBase + tt_ * 32;                                \
    char* da_ = ldsA + (BI) * 32768 + stgOffA;                                  \
    char* dw_ = ldsW + (BI) * 16384 + stgOffW;                                  \
    _Pragma("unroll")                                                           \
    for (int i = 0; i < 4; ++i)                                                 \
      gload16(as_ + i * (8 * D_N), da_ + i * 1024);                             \
    _Pragma("unroll")                                                           \
    for (int i = 0; i < 2; ++i)                                                 \
      gload16(ws_ + i * (8 * K_N), dw_ + i * 1024);                             \
  }

  // ---- prologue: batches 0,1 in flight (12 outstanding per wave) ----
  ISSUE(0, 0)
  ISSUE(1, 1)

  int cur = 0;   // t % 3
#pragma unroll 1
  for (int t = 0; t < NSTEPS; ++t) {
    // ledger/wave (L=6/step), top of iter t (oldest->newest):
    //   steady [L(t)6, S(t-2)4, L(t+1)6, S(t-1)4] -> force L(t) = WAITV(14)
    if (t == 0)               { WAITV(6);  }
    else if (t == 1)          { WAITV(10); }
    else if (t == NSTEPS - 1) { WAITV(8);  }
    else                      { WAITV(14); }
    BAR();   // all waves' L(t) landed; all waves' t-1 reads consumed (data-dep lgkm)

    const int ib = (cur == 0) ? 2 : cur - 1;   // (t+2) % 3

    // ---- swizzled ds_read of my fragments (f32); compiler counts lgkm ----
    const char* rbA = ldsA + cur * 32768;
    const char* rbW = ldsW + cur * 16384;
    f32x4 alo[4], ahi[4], wlo[4], whi[4];
#pragma unroll
    for (int i = 0; i < 4; ++i) {
      const int Ra = (wr + i * 16 + l15) * 128;
      alo[i] = *(const f32x4*)(rbA + Ra + rd0);
      ahi[i] = *(const f32x4*)(rbA + Ra + rd1);
      const int Rw = (wc + i * 16 + l15) * 128;
      wlo[i] = *(const f32x4*)(rbW + Rw + rd0);
      whi[i] = *(const f32x4*)(rbW + Rw + rd1);
    }

    // ---- batch t+2 into ring slot ib (different buffer than cur: no wait needed) ----
    if (t + 2 < NSTEPS) ISSUE(t + 2, ib)

    // ---- fill stores (newest in queue; never forced by any WAITV) ----
#pragma unroll
    for (int s = 0; s < 4; ++s) {
      const int li = t * 2048 + s * 512 + tid;     // block-local f32x4 idx
      const int gi = sb * 65536 + li;
      const int col4 = (gi & 1023) << 2;
      const int l_   = (gi >> 10) & 4095;
      f32x4 v;
      v.x = (col4     == l_) ? 1.0f : 0.0f;
      v.y = (col4 + 1 == l_) ? 1.0f : 0.0f;
      v.z = (col4 + 2 == l_) ? 1.0f : 0.0f;
      v.w = (col4 + 3 == l_) ? 1.0f : 0.0f;
      __builtin_nontemporal_store(v, attn4 + li);
    }

    // ---- cvt + 16 MFMA (compiler inserts counted lgkm before first use) ----
    bf16x8 af[4], wf[4];
#pragma unroll
    for (int i = 0; i < 4; ++i) {
      af[i] = pack8(alo[i], ahi[i]);
      wf[i] = pack8(wlo[i], whi[i]);
    }
#pragma unroll
    for (int i = 0; i < 4; ++i)
#pragma unroll
      for (int j = 0; j < 4; ++j)
        acc[i][j] = __builtin_amdgcn_mfma_f32_16x16x32_bf16(af[i], wf[j], acc[i][j], 0, 0, 0);

    cur = (cur == 2) ? 0 : cur + 1;
  }
#undef ISSUE

  // ---- epilogue: C/D layout col=lane&15, row=(lane>>4)*4+reg (verified R1/m89/m91) ----
  const int r0  = m0 + wr + (lq << 2);
  const int c0g = n0 + wc + l15;
  float bv[4];
#pragma unroll
  for (int j = 0; j < 4; ++j) bv[j] = bias[c0g + j * 16];
#pragma unroll
  for (int i = 0; i < 4; ++i)
#pragma unroll
    for (int j = 0; j < 4; ++j)
#pragma unroll
      for (int r = 0; r < 4; ++r) {
        const int m = r0 + i * 16 + r;
        const int n = c0g + j * 16;
        dout[(size_t)m * D_N + n] = tanhf(acc[i][j][r] + bv[j]);
      }
}

extern "C" void kernel_launch(void* const* d_in, const int* in_sizes, int n_in,
                              void* d_out, int out_size, void* d_ws, size_t ws_size,
                              hipStream_t stream) {
  const float* outp = (const float*)d_in[0];
  const float* ctx  = (const float*)d_in[1];
  const float* Wm   = (const float*)d_in[2];
  const float* bias = (const float*)d_in[3];
  float* dout = (float*)d_out;
  hipLaunchKernelGGL(gemm_fill, dim3(NBLOCKS), dim3(NTHREADS), 0, stream,
                     outp, ctx, Wm, bias, dout);
}